// Round 8
// baseline (649.770 us; speedup 1.0000x reference)
//
#include <hip/hip_runtime.h>
#include <math.h>

// StatisticalFeatureLoss — R7: ALL THREE window sizes fused into one sweep.
// Law from R1-R6: per wave-iteration cost is K-independent (loads + emit
// chain + scaffolding dominate). So pay it once: each row iteration feeds
// three independent scatter-ring pipelines (K=3,5,7; D=4/12/12, folding
// under one U=12 unroll). Shared x loads & x-ring. Zero LDS arrays.

static constexpr int H = 512, W = 512, PLANES = 48;
static constexpr float EPSF = 1e-8f;
static constexpr int BAND = 128, NBAND = H / BAND;   // 4
static constexpr int OW = 52, NSTRIP = 10;           // 52*10 = 520 >= 512
static constexpr int T  = BAND + 12;                 // last emit (K=7) at i=BAND+11
static constexpr int Tp = ((T + 11) / 12) * 12;      // 144

__global__ void init_acc_kernel(double* acc) {
    if (threadIdx.x < 4) acc[threadIdx.x] = 0.0;
}

__global__ void final_kernel(const double* __restrict__ acc, float* __restrict__ out) {
    if (threadIdx.x == 0) {
        const double npix = (double)PLANES * H * W;
        double tot = acc[0] + acc[1] + 0.5 * acc[2] + 0.001 * acc[3];
        out[0] = (float)(tot / (npix * 12.0));
    }
}

__device__ __forceinline__ float bperm(int addr, float v) {
    return __int_as_float(__builtin_amdgcn_ds_bpermute(addr, __float_as_int(v)));
}

// One tensor-iteration of the K-pipeline. u is a literal after unroll, so
// every (u+c)%DK ring index folds to a constant. Slot(r) = (r - y0) mod DK.
// Row y scatter: mn/msq rows y-R..y+R (d==K-1 overwrites, ring invariant);
// mean[y-R] completes this iter -> xcm -> v3/v4 -> scatter rows y-2R..y;
// emit row y-2R (m3a/m4a complete via this iter's d==0 term).
template <int K, int DK>
__device__ __forceinline__ void kstep(
    int u, int t, float x, float rmask, bool okEmit,
    const float* __restrict__ g, const float (&xrs)[4],
    float (&mn)[DK], float (&msq)[DK], float (&m3a)[DK], float (&m4a)[DK],
    float (&featp)[4], float (&sums)[4], int s)
{
    constexpr int R = K / 2;
    float w[K];
#pragma unroll
    for (int j = 0; j < K; ++j)
        w[j] = (j == R) ? x : bperm((t - R + j) << 2, x);
    float hx = 0.f, hq = 0.f;
#pragma unroll
    for (int j = 0; j < K; ++j) { hx += g[j] * w[j]; hq += g[j] * (w[j] * w[j]); }
#pragma unroll
    for (int d = 0; d < K; ++d) {
        const int sl = (u + d - R + 4 * DK) % DK;
        if (d == K - 1) { mn[sl] = g[d] * hx; msq[sl] = g[d] * hq; }
        else            { mn[sl] += g[d] * hx; msq[sl] += g[d] * hq; }
    }
    const float xold  = xrs[(u - R + 8) & 3];
    const float mean1 = mn[(u - R + 4 * DK) % DK];
    const float xcm   = (xold - mean1) * rmask;   // zero-padded xc field
    float wc[K];
#pragma unroll
    for (int j = 0; j < K; ++j)
        wc[j] = (j == R) ? xcm : bperm((t - R + j) << 2, xcm);
    float v3 = 0.f, v4 = 0.f;
#pragma unroll
    for (int j = 0; j < K; ++j) {
        const float c2 = wc[j] * wc[j];
        v3 += g[j] * (c2 * wc[j]);
        v4 += g[j] * (c2 * c2);
    }
#pragma unroll
    for (int d = 0; d < K; ++d) {
        const int sl = (u + d - 2 * R + 4 * DK) % DK;
        if (d == K - 1) { m3a[sl] = g[d] * v3; m4a[sl] = g[d] * v4; }
        else            { m3a[sl] += g[d] * v3; m4a[sl] += g[d] * v4; }
    }
    if (okEmit) {
        const int se = (u - 2 * R + 4 * DK) % DK;
        const float mean = mn[se];
        const float var  = fmaxf(msq[se] - mean * mean, EPSF);
        const float sd   = sqrtf(var);
        const float skew = __fdividef(m3a[se], sd * var + EPSF);
        const float kurt = __fdividef(m4a[se], var * var + EPSF);
        if (s == 0) {
            featp[0] = mean; featp[1] = var; featp[2] = skew; featp[3] = kurt;
        } else {
            sums[0] += fabsf(featp[0] - mean);
            sums[1] += fabsf(featp[1] - var);
            sums[2] += fabsf(featp[2] - skew);
            sums[3] += fabsf(featp[3] - kurt);
        }
    }
}

__global__ __launch_bounds__(256)
void stat_kernel(const float* __restrict__ pred, const float* __restrict__ targ,
                 double* __restrict__ acc) {
    const int wv    = threadIdx.x >> 6;
    const int wid   = blockIdx.x * 4 + wv;       // [0, 1920)
    const int band  = wid % NBAND;
    const int tmp   = wid / NBAND;
    const int strip = tmp % NSTRIP;
    const int plane = tmp / NSTRIP;
    const int t     = threadIdx.x & 63;
    const int gc0   = strip * OW - 6 + t;        // unified halo 6 (= 2*Rmax)
    const int y0    = band * BAND - 6;

    const bool  iva     = (unsigned)gc0 < (unsigned)W;
    const float colmask = iva ? 1.f : 0.f;
    const float emask   = (t >= 6 && t < 6 + OW && gc0 < W) ? 1.f : 0.f;

    // Gaussian weights (reference numerics), lane-uniform in SGPRs
    float g3[3], g5[5], g7[7];
    {
        auto build = [&](float* g, int K) {
            const float sigma = (float)K / 6.0f;
            const float inv2s2 = 1.0f / (2.0f * sigma * sigma);
            float s = 0.0f;
            for (int i = 0; i < K; ++i) {
                float c = (float)(i - K / 2);
                g[i] = expf(-c * c * inv2s2);
                s += g[i];
            }
            for (int i = 0; i < K; ++i)
                g[i] = __int_as_float(__builtin_amdgcn_readfirstlane(__float_as_int(g[i] / s)));
        };
        build(g3, 3); build(g5, 5); build(g7, 7);
    }

    const float* src0 = pred + (size_t)plane * H * W + gc0;
    const float* src1 = targ + (size_t)plane * H * W + gc0;

    auto loadrow = [&](int s, int y) -> float {
        float v = 0.f;
        if (iva && (unsigned)y < (unsigned)H)
            v = (s == 0 ? src0 : src1)[(long)y << 9];
        return v;
    };

    // Per-tensor rings. Zero-init keeps warmup reads finite (any warmup
    // garbage lands only in rows < band start, cleansed by ring overwrite).
    float xr[2][4];
    float mn3[2][4]  = {}, msq3[2][4]  = {}, m33[2][4]  = {}, m43[2][4]  = {};
    float mn5[2][12] = {}, msq5[2][12] = {}, m35[2][12] = {}, m45[2][12] = {};
    float mn7[2][12] = {}, msq7[2][12] = {}, m37[2][12] = {}, m47[2][12] = {};
    float fp3[4], fp5[4], fp7[4];
    float sums[4] = {0.f, 0.f, 0.f, 0.f};
    float pf[2] = { loadrow(0, y0), loadrow(1, y0) };
    xr[0][3] = 0.f; xr[1][3] = 0.f; xr[0][2] = 0.f; xr[1][2] = 0.f;
    xr[0][1] = 0.f; xr[1][1] = 0.f; xr[0][0] = 0.f; xr[1][0] = 0.f;

    for (int yy = 0; yy < Tp; yy += 12) {
#pragma unroll
        for (int u = 0; u < 12; ++u) {
            const int i = yy + u;          // i % 12 == u  (12 | yy)
            const int y = y0 + i;
            const float rm1 = (((unsigned)(y - 1) < (unsigned)H) ? 1.f : 0.f) * colmask;
            const float rm2 = (((unsigned)(y - 2) < (unsigned)H) ? 1.f : 0.f) * colmask;
            const float rm3 = (((unsigned)(y - 3) < (unsigned)H) ? 1.f : 0.f) * colmask;
            const bool e3 = (i >= 8)  && (i < 8 + BAND);
            const bool e5 = (i >= 10) && (i < 10 + BAND);
            const bool e7 = (i >= 12) && (i < 12 + BAND);
#pragma unroll
            for (int s = 0; s < 2; ++s) {
                const float x = pf[s];
                pf[s] = loadrow(s, y + 1);
                xr[s][u & 3] = x;
                kstep<3, 4>(u, t, x, rm1, e3, g3, xr[s],
                            mn3[s], msq3[s], m33[s], m43[s], fp3, sums, s);
                kstep<5, 12>(u, t, x, rm2, e5, g5, xr[s],
                             mn5[s], msq5[s], m35[s], m45[s], fp5, sums, s);
                kstep<7, 12>(u, t, x, rm3, e7, g7, xr[s],
                             mn7[s], msq7[s], m37[s], m47[s], fp7, sums, s);
            }
        }
    }

    // per-wave reduction, one cross-wave LDS pass, 4 atomics per block
    __shared__ float red[4][4];
#pragma unroll
    for (int f = 0; f < 4; ++f) {
        float v = sums[f] * emask;
#pragma unroll
        for (int off = 32; off > 0; off >>= 1) v += __shfl_down(v, off, 64);
        if (t == 0) red[wv][f] = v;
    }
    __syncthreads();
    if (threadIdx.x < 4) {
        float v = red[0][threadIdx.x] + red[1][threadIdx.x]
                + red[2][threadIdx.x] + red[3][threadIdx.x];
        atomicAdd(&acc[threadIdx.x], (double)v);
    }
}

extern "C" void kernel_launch(void* const* d_in, const int* in_sizes, int n_in,
                              void* d_out, int out_size, void* d_ws, size_t ws_size,
                              hipStream_t stream) {
    const float* pred = (const float*)d_in[0];
    const float* targ = (const float*)d_in[1];
    double* acc = (double*)d_ws;
    float* out = (float*)d_out;

    init_acc_kernel<<<1, 64, 0, stream>>>(acc);

    // 48 planes * 10 strips * 4 bands = 1920 waves = 480 blocks of 4 waves
    stat_kernel<<<dim3(PLANES * NSTRIP * NBAND / 4), 256, 0, stream>>>(pred, targ, acc);

    final_kernel<<<1, 64, 0, stream>>>(acc, out);
}